// Round 4
// baseline (1328.106 us; speedup 1.0000x reference)
//
#include <hip/hip_runtime.h>

// Problem constants (B,S,D,H from reference)
#define B_ 2
#define S_ 2048
#define D_ 1024
#define H_ 16
#define DK_ 64
#define M_ (B_ * S_)      // 4096 rows in the projection GEMMs
#define JC 256            // j-chunk for attention sweep 2

typedef __bf16 bf16;
typedef __attribute__((ext_vector_type(8))) __bf16 bf16x8;
typedef __attribute__((ext_vector_type(4))) float f32x4;

static __device__ __forceinline__ bf16x8 ld8(const bf16* p) {
    return *(const bf16x8*)p;   // 16B aligned by construction
}
// load 8 fp32, round to a bf16x8 MFMA fragment
static __device__ __forceinline__ bf16x8 ld8f(const float* p) {
    f32x4 a = *(const f32x4*)p;
    f32x4 b = *(const f32x4*)(p + 4);
    bf16x8 r;
    r[0] = (bf16)a[0]; r[1] = (bf16)a[1]; r[2] = (bf16)a[2]; r[3] = (bf16)a[3];
    r[4] = (bf16)b[0]; r[5] = (bf16)b[1]; r[6] = (bf16)b[2]; r[7] = (bf16)b[3];
    return r;
}

// ---------------------------------------------------------------------------
// QKV projection GEMM: X (fp32, MxD row-major), W (fp32, NxD), bias (fp32).
// Y (bf16) written in head-split (B,H,S,DK) layout.
// ---------------------------------------------------------------------------
__global__ __launch_bounds__(256)
void gemm_qkv(const float* __restrict__ X, const float* __restrict__ W,
              const float* __restrict__ bias, bf16* __restrict__ Y)
{
    const int m0   = blockIdx.x * 64;
    const int n0   = blockIdx.y * 64;
    const int wave = threadIdx.x >> 6;
    const int lane = threadIdx.x & 63;
    const int quad = lane >> 4;
    const int l16  = lane & 15;

    f32x4 acc[4] = {{0.f,0.f,0.f,0.f},{0.f,0.f,0.f,0.f},
                    {0.f,0.f,0.f,0.f},{0.f,0.f,0.f,0.f}};

    const float* xrow = X + (size_t)(m0 + wave*16 + l16) * D_;
    for (int k0 = 0; k0 < D_; k0 += 32) {
        const int ka = k0 + quad*8;
        bf16x8 a = ld8f(xrow + ka);
#pragma unroll
        for (int t = 0; t < 4; ++t) {
            bf16x8 b = ld8f(W + (size_t)(n0 + t*16 + l16) * D_ + ka);
            acc[t] = __builtin_amdgcn_mfma_f32_16x16x32_bf16(a, b, acc[t], 0, 0, 0);
        }
    }

#pragma unroll
    for (int t = 0; t < 4; ++t) {
        const int nn = n0 + t*16 + l16;
        const float bv = bias[nn];
#pragma unroll
        for (int r = 0; r < 4; ++r) {
            const int mm = m0 + wave*16 + quad*4 + r;
            int bb = mm >> 11, ss = mm & (S_ - 1);
            int hh = nn >> 6,  dd = nn & (DK_ - 1);
            Y[(((size_t)(bb * H_ + hh) * S_ + ss) * DK_ + dd)] = (bf16)(acc[t][r] + bv);
        }
    }
}

// ---------------------------------------------------------------------------
// Output projection GEMM: X = ctx (bf16, stored head-split in Q's buffer),
// W = Wo (fp32, NxD), bias fp32 -> out (fp32, MxD flat).
// ---------------------------------------------------------------------------
__global__ __launch_bounds__(256)
void gemm_out(const bf16* __restrict__ X, const float* __restrict__ W,
              const float* __restrict__ bias, float* __restrict__ Y)
{
    const int m0   = blockIdx.x * 64;
    const int n0   = blockIdx.y * 64;
    const int wave = threadIdx.x >> 6;
    const int lane = threadIdx.x & 63;
    const int quad = lane >> 4;
    const int l16  = lane & 15;

    f32x4 acc[4] = {{0.f,0.f,0.f,0.f},{0.f,0.f,0.f,0.f},
                    {0.f,0.f,0.f,0.f},{0.f,0.f,0.f,0.f}};

    const int mm_a = m0 + wave*16 + l16;
    const int bb_a = mm_a >> 11, ss_a = mm_a & (S_ - 1);
    for (int k0 = 0; k0 < D_; k0 += 32) {
        const int ka = k0 + quad*8;           // 8-aligned, never crosses a head
        const int hh = ka >> 6, dd = ka & (DK_ - 1);
        bf16x8 a = ld8(X + (((size_t)(bb_a * H_ + hh) * S_ + ss_a) * DK_ + dd));
#pragma unroll
        for (int t = 0; t < 4; ++t) {
            bf16x8 b = ld8f(W + (size_t)(n0 + t*16 + l16) * D_ + ka);
            acc[t] = __builtin_amdgcn_mfma_f32_16x16x32_bf16(a, b, acc[t], 0, 0, 0);
        }
    }

#pragma unroll
    for (int t = 0; t < 4; ++t) {
        const int nn = n0 + t*16 + l16;
        const float bv = bias[nn];
#pragma unroll
        for (int r = 0; r < 4; ++r) {
            const int mm = m0 + wave*16 + quad*4 + r;
            Y[(size_t)mm * D_ + nn] = acc[t][r] + bv;
        }
    }
}

// ---------------------------------------------------------------------------
// Fused attention: one block per (q-tile16, b). Sweep 1: softmax denominators
// (wave w handles heads {w,w+4,w+8,w+12}, full S). Sweep 2: recompute P per
// (chunk, head); head-mean weights -> fp32 attnOut; ctx -> registers, then
// overwrite the block's own 16 Q rows (bf16, head-split; no other block reads
// them). NaN-proof clamps retained.
// ---------------------------------------------------------------------------
__global__ __launch_bounds__(256)
void attn_fused(const bf16* __restrict__ Q, const bf16* __restrict__ K,
                const bf16* __restrict__ V, bf16* __restrict__ ctxOutQ,
                float* __restrict__ attnOut)
{
    const int q0 = blockIdx.x * 16;
    const int b  = blockIdx.y;
    const int tid  = threadIdx.x;
    const int wave = tid >> 6;
    const int lane = tid & 63;
    const int quad = lane >> 4;
    const int l16  = lane & 15;

    __shared__ float attnsum[16][JC];      // 16 KB
    __shared__ bf16  Plds[16][JC + 8];     // 8.25 KB
    __shared__ bf16  Vt[DK_][JC + 8];      // 33 KB
    __shared__ float linv[H_][16];         // 1 KB

    // ---- sweep 1: denominators ----
#pragma unroll
    for (int hh = 0; hh < 4; ++hh) {
        const int h = wave + hh * 4;
        const bf16* qrow = Q + ((size_t)(b * H_ + h) * S_ + q0 + l16) * DK_;
        bf16x8 qf0 = ld8(qrow + quad*8);
        bf16x8 qf1 = ld8(qrow + 32 + quad*8);
        const bf16* Kb = K + (size_t)(b * H_ + h) * S_ * DK_;

        float lsum[4] = {0.f, 0.f, 0.f, 0.f};
        for (int jt = 0; jt < S_/16; ++jt) {
            const bf16* krow = Kb + (size_t)(jt*16 + l16) * DK_;
            bf16x8 kf0 = ld8(krow + quad*8);
            bf16x8 kf1 = ld8(krow + 32 + quad*8);
            f32x4 acc = {0.f,0.f,0.f,0.f};
            acc = __builtin_amdgcn_mfma_f32_16x16x32_bf16(qf0, kf0, acc, 0, 0, 0);
            acc = __builtin_amdgcn_mfma_f32_16x16x32_bf16(qf1, kf1, acc, 0, 0, 0);
#pragma unroll
            for (int r = 0; r < 4; ++r)
                lsum[r] += __expf(fminf(acc[r] * 0.125f, 60.f));
        }
#pragma unroll
        for (int d = 1; d < 16; d <<= 1) {
#pragma unroll
            for (int r = 0; r < 4; ++r)
                lsum[r] += __shfl_xor(lsum[r], d);
        }
        if (l16 == 0) {
#pragma unroll
            for (int r = 0; r < 4; ++r)
                linv[h][quad*4 + r] = 1.0f / fmaxf(lsum[r], 1e-30f);
        }
    }
    __syncthreads();

    // ---- sweep 2: P, head-mean weights, ctx ----
    f32x4 ctx[H_];
#pragma unroll
    for (int h = 0; h < H_; ++h) ctx[h] = f32x4{0.f,0.f,0.f,0.f};

    for (int c = 0; c < S_/JC; ++c) {
        const int j0 = c * JC;
        for (int i = tid; i < 16*JC; i += 256) ((float*)attnsum)[i] = 0.f;
        __syncthreads();

        for (int h = 0; h < H_; ++h) {
            const bf16* qrow = Q + ((size_t)(b * H_ + h) * S_ + q0 + l16) * DK_;
            bf16x8 qf0 = ld8(qrow + quad*8);
            bf16x8 qf1 = ld8(qrow + 32 + quad*8);
            const bf16* Kb = K + (size_t)(b * H_ + h) * S_ * DK_;
            const bf16* Vb = V + (size_t)(b * H_ + h) * S_ * DK_;

#pragma unroll
            for (int t = 0; t < 4; ++t) {
                const int jl = (wave*4 + t) * 16;
                const bf16* krow = Kb + (size_t)(j0 + jl + l16) * DK_;
                bf16x8 kf0 = ld8(krow + quad*8);
                bf16x8 kf1 = ld8(krow + 32 + quad*8);
                f32x4 acc = {0.f,0.f,0.f,0.f};
                acc = __builtin_amdgcn_mfma_f32_16x16x32_bf16(qf0, kf0, acc, 0, 0, 0);
                acc = __builtin_amdgcn_mfma_f32_16x16x32_bf16(qf1, kf1, acc, 0, 0, 0);
#pragma unroll
                for (int r = 0; r < 4; ++r) {
                    const int row = quad*4 + r;
                    const int col = jl + l16;
                    float p = __expf(fminf(acc[r] * 0.125f, 60.f)) * linv[h][row];
                    p = fminf(p, 1.0f);
                    attnsum[row][col] += p * (1.0f / H_);
                    Plds[row][col] = (bf16)p;
                }
            }
            // stage V^T (lane -> dk)
            for (int jl0 = wave * 8; jl0 < JC; jl0 += 32) {
                bf16x8 tmp;
#pragma unroll
                for (int e = 0; e < 8; ++e)
                    tmp[e] = Vb[(size_t)(j0 + jl0 + e) * DK_ + lane];
                *(bf16x8*)(&Vt[lane][jl0]) = tmp;
            }
            __syncthreads();

            // PV: wave w owns dk slice [16w,16w+16)
            f32x4 cacc = ctx[h];
#pragma unroll
            for (int ks = 0; ks < JC/32; ++ks) {
                bf16x8 a  = *(const bf16x8*)(&Plds[l16][ks*32 + quad*8]);
                bf16x8 bv = *(const bf16x8*)(&Vt[wave*16 + l16][ks*32 + quad*8]);
                cacc = __builtin_amdgcn_mfma_f32_16x16x32_bf16(a, bv, cacc, 0, 0, 0);
            }
            ctx[h] = cacc;
            __syncthreads();
        }

        for (int i = tid; i < 16*JC; i += 256) {
            int row = i >> 8, col = i & (JC - 1);
            attnOut[((size_t)b * S_ + q0 + row) * S_ + j0 + col] = attnsum[row][col];
        }
        __syncthreads();
    }

    // ---- write ctx over this block's own Q rows (head-split layout) ----
#pragma unroll
    for (int h = 0; h < H_; ++h) {
#pragma unroll
        for (int r = 0; r < 4; ++r) {
            size_t addr = ((size_t)(b * H_ + h) * S_ + q0 + quad*4 + r) * DK_
                        + wave*16 + l16;
            ctxOutQ[addr] = (bf16)ctx[h][r];
        }
    }
}

// ---------------------------------------------------------------------------
extern "C" void kernel_launch(void* const* d_in, const int* in_sizes, int n_in,
                              void* d_out, int out_size, void* d_ws, size_t ws_size,
                              hipStream_t stream)
{
    (void)in_sizes; (void)n_in; (void)out_size; (void)ws_size;

    const float* query = (const float*)d_in[0];
    const float* key_t = (const float*)d_in[1];
    const float* value = (const float*)d_in[2];
    const float* Wq = (const float*)d_in[3];
    const float* bq = (const float*)d_in[4];
    const float* Wk = (const float*)d_in[5];
    const float* bk = (const float*)d_in[6];
    const float* Wv = (const float*)d_in[7];
    const float* bv = (const float*)d_in[8];
    const float* Wo = (const float*)d_in[9];
    const float* bo = (const float*)d_in[10];

    float* out     = (float*)d_out;                  // (B,S,D) fp32
    float* attnOut = out + (size_t)B_ * S_ * D_;     // (B,S,S) fp32

    const size_t nQ = (size_t)B_ * S_ * D_;          // 4.19M elements
    bf16* Qh = (bf16*)d_ws;                          // ws: 3*nQ*2B = 25.2 MB
    bf16* Kh = Qh + nQ;
    bf16* Vh = Kh + nQ;

    dim3 gg(M_/64, D_/64);
    gemm_qkv<<<gg, 256, 0, stream>>>(query, Wq, bq, Qh);
    gemm_qkv<<<gg, 256, 0, stream>>>(key_t, Wk, bk, Kh);
    gemm_qkv<<<gg, 256, 0, stream>>>(value, Wv, bv, Vh);
    attn_fused<<<dim3(S_/16, B_), 256, 0, stream>>>(Qh, Kh, Vh, Qh, attnOut);
    // ctx now lives in Qh (bf16, head-split); output projection reads it there
    gemm_out<<<gg, 256, 0, stream>>>(Qh, Wo, bo, out);
}

// Round 5
// 667.633 us; speedup vs baseline: 1.9893x; 1.9893x over previous
//
#include <hip/hip_runtime.h>

// Problem constants (B,S,D,H from reference)
#define B_ 2
#define S_ 2048
#define D_ 1024
#define H_ 16
#define DK_ 64
#define M_ (B_ * S_)      // 4096 rows in the projection GEMMs

typedef __bf16 bf16;
typedef __attribute__((ext_vector_type(8))) __bf16 bf16x8;
typedef __attribute__((ext_vector_type(4))) float f32x4;

static __device__ __forceinline__ bf16x8 ld8(const bf16* p) {
    return *(const bf16x8*)p;   // 16B aligned by construction
}

// ---------------------------------------------------------------------------
// Elementwise fp32 -> bf16 for the 3 X inputs (into d_out scratch) and the
// 4 weight matrices (into ws). Block mapping: 3*2048 X-blocks + 4*512 W-blocks.
// ---------------------------------------------------------------------------
__global__ __launch_bounds__(256)
void cvt_all(const float* __restrict__ xq, const float* __restrict__ xk,
             const float* __restrict__ xv, const float* __restrict__ wq,
             const float* __restrict__ wk, const float* __restrict__ wv,
             const float* __restrict__ wo, bf16* __restrict__ xqo,
             bf16* __restrict__ xko, bf16* __restrict__ xvo,
             bf16* __restrict__ wqo, bf16* __restrict__ wko,
             bf16* __restrict__ wvo, bf16* __restrict__ woo)
{
    const int bx = blockIdx.x;
    const float* s; bf16* d; size_t base;
    if (bx < 6144) {
        int a = bx >> 11;                      // /2048
        s = (a == 0) ? xq : (a == 1) ? xk : xv;
        d = (a == 0) ? xqo : (a == 1) ? xko : xvo;
        base = (size_t)(bx & 2047) * 2048;
    } else {
        int a = (bx - 6144) >> 9;              // /512
        s = (a == 0) ? wq : (a == 1) ? wk : (a == 2) ? wv : wo;
        d = (a == 0) ? wqo : (a == 1) ? wko : (a == 2) ? wvo : woo;
        base = (size_t)((bx - 6144) & 511) * 2048;
    }
    size_t i = base + (size_t)threadIdx.x * 8;
    f32x4 a4 = *(const f32x4*)(s + i);
    f32x4 b4 = *(const f32x4*)(s + i + 4);
    bf16x8 r;
    r[0]=(bf16)a4[0]; r[1]=(bf16)a4[1]; r[2]=(bf16)a4[2]; r[3]=(bf16)a4[3];
    r[4]=(bf16)b4[0]; r[5]=(bf16)b4[1]; r[6]=(bf16)b4[2]; r[7]=(bf16)b4[3];
    *(bf16x8*)(d + i) = r;
}

// ---------------------------------------------------------------------------
// 128x128-tile bf16 GEMM, LDS-staged, 2-barrier K-loop (m92/m97 lineage).
// Y[m,n] = sum_k A[m,k]*W[n,k] + bias[n].  4 waves in 2x2, each 64x64.
// a_headsplit: A element (m,k) lives at ((b*H+h)*S+s)*DK+dk (ctx layout).
// out_f32: write fp32 flat; else bf16 head-split (B,H,S,DK).
// ---------------------------------------------------------------------------
__global__ __launch_bounds__(256)
void gemm128(const bf16* __restrict__ A, const bf16* __restrict__ W,
             const float* __restrict__ bias, void* __restrict__ out,
             int a_headsplit, int out_f32)
{
    const int m0 = blockIdx.x * 128, n0 = blockIdx.y * 128;
    const int tid = threadIdx.x;
    const int wv = tid >> 6, lane = tid & 63, quad = lane >> 4, l16 = lane & 15;
    const int wr = (wv >> 1) * 64, wc = (wv & 1) * 64;

    __shared__ bf16 As[128 * 32];
    __shared__ bf16 Bs[128 * 32];

    f32x4 acc[4][4];
#pragma unroll
    for (int i = 0; i < 4; ++i)
#pragma unroll
        for (int j = 0; j < 4; ++j) acc[i][j] = f32x4{0.f, 0.f, 0.f, 0.f};

    const int srow = tid >> 2;            // 0..63
    const int scol = (tid & 3) * 8;       // 0,8,16,24

    for (int k0 = 0; k0 < D_; k0 += 32) {
        // global loads to regs first (overlap with previous compute)
        bf16x8 av[2], bw[2];
#pragma unroll
        for (int c = 0; c < 2; ++c) {
            const int row = c * 64 + srow;
            const int k   = k0 + scol;
            const bf16* ap;
            if (a_headsplit) {
                int m = m0 + row, bb = m >> 11, ss = m & (S_ - 1);
                int hh = k >> 6, dd = k & (DK_ - 1);
                ap = A + (((size_t)(bb * H_ + hh) * S_ + ss) * DK_ + dd);
            } else {
                ap = A + (size_t)(m0 + row) * D_ + k;
            }
            av[c] = ld8(ap);
            bw[c] = ld8(W + (size_t)(n0 + row) * D_ + k);
        }
        __syncthreads();   // previous iteration's fragment reads done
#pragma unroll
        for (int c = 0; c < 2; ++c) {
            const int e = c * 2048 + tid * 8;
            *(bf16x8*)(As + e) = av[c];
            *(bf16x8*)(Bs + e) = bw[c];
        }
        __syncthreads();   // tiles visible

        bf16x8 af[4], bfr[4];
#pragma unroll
        for (int i = 0; i < 4; ++i)
            af[i] = *(const bf16x8*)(As + (wr + i*16 + l16) * 32 + quad * 8);
#pragma unroll
        for (int j = 0; j < 4; ++j)
            bfr[j] = *(const bf16x8*)(Bs + (wc + j*16 + l16) * 32 + quad * 8);
#pragma unroll
        for (int i = 0; i < 4; ++i)
#pragma unroll
            for (int j = 0; j < 4; ++j)
                acc[i][j] = __builtin_amdgcn_mfma_f32_16x16x32_bf16(
                    af[i], bfr[j], acc[i][j], 0, 0, 0);
    }

#pragma unroll
    for (int i = 0; i < 4; ++i)
#pragma unroll
        for (int j = 0; j < 4; ++j) {
            const int nn = n0 + wc + j*16 + l16;
            const float bvv = bias[nn];
#pragma unroll
            for (int r = 0; r < 4; ++r) {
                const int mm = m0 + wr + i*16 + quad*4 + r;
                float v = acc[i][j][r] + bvv;
                if (out_f32) {
                    ((float*)out)[(size_t)mm * D_ + nn] = v;
                } else {
                    int bb = mm >> 11, ss = mm & (S_ - 1);
                    int hh = nn >> 6, dd = nn & (DK_ - 1);
                    ((bf16*)out)[((size_t)(bb * H_ + hh) * S_ + ss) * DK_ + dd] = (bf16)v;
                }
            }
        }
}

// ---------------------------------------------------------------------------
// Softmax denominators: one block per (q-tile16, head, b); waves split j.
// ---------------------------------------------------------------------------
__global__ __launch_bounds__(256)
void attn_sum(const bf16* __restrict__ Q, const bf16* __restrict__ K,
              float* __restrict__ Lo)
{
    const int q0 = blockIdx.x * 16, h = blockIdx.y, b = blockIdx.z;
    const int wv = threadIdx.x >> 6, lane = threadIdx.x & 63;
    const int quad = lane >> 4, l16 = lane & 15;

    const bf16* qrow = Q + ((size_t)(b * H_ + h) * S_ + q0 + l16) * DK_;
    bf16x8 qf0 = ld8(qrow + quad*8), qf1 = ld8(qrow + 32 + quad*8);
    const bf16* Kb = K + (size_t)(b * H_ + h) * S_ * DK_;

    float lsum[4] = {0.f, 0.f, 0.f, 0.f};
    for (int jt = wv; jt < S_/16; jt += 4) {
        const bf16* krow = Kb + (size_t)(jt*16 + l16) * DK_;
        bf16x8 kf0 = ld8(krow + quad*8), kf1 = ld8(krow + 32 + quad*8);
        f32x4 s = {0.f,0.f,0.f,0.f};
        s = __builtin_amdgcn_mfma_f32_16x16x32_bf16(qf0, kf0, s, 0, 0, 0);
        s = __builtin_amdgcn_mfma_f32_16x16x32_bf16(qf1, kf1, s, 0, 0, 0);
#pragma unroll
        for (int r = 0; r < 4; ++r)
            lsum[r] += __expf(fminf(s[r] * 0.125f, 60.f));
    }
#pragma unroll
    for (int d = 1; d < 16; d <<= 1)
#pragma unroll
        for (int r = 0; r < 4; ++r) lsum[r] += __shfl_xor(lsum[r], d);

    __shared__ float wp[4][16];
    if (l16 == 0)
#pragma unroll
        for (int r = 0; r < 4; ++r) wp[wv][quad*4 + r] = lsum[r];
    __syncthreads();
    if (threadIdx.x < 16) {
        int row = threadIdx.x;
        Lo[(size_t)(b * H_ + h) * S_ + q0 + row] =
            wp[0][row] + wp[1][row] + wp[2][row] + wp[3][row];
    }
}

// ---------------------------------------------------------------------------
// Head-mean attention weights: one block per (q-tile16, j-chunk256, b).
// Accumulates over all 16 heads in registers; no inner barriers.
// ---------------------------------------------------------------------------
__global__ __launch_bounds__(256)
void attn_weights(const bf16* __restrict__ Q, const bf16* __restrict__ K,
                  const float* __restrict__ Li, float* __restrict__ attnOut)
{
    const int q0 = blockIdx.x * 16, j0 = blockIdx.y * 256, b = blockIdx.z;
    const int tid = threadIdx.x;
    const int wv = tid >> 6, lane = tid & 63, quad = lane >> 4, l16 = lane & 15;

    __shared__ float linv[H_][16];
    {
        int h = tid >> 4, row = tid & 15;
        linv[h][row] = 1.0f / fmaxf(Li[(size_t)(b * H_ + h) * S_ + q0 + row], 1e-30f);
    }
    __syncthreads();

    f32x4 asum[4];
#pragma unroll
    for (int t = 0; t < 4; ++t) asum[t] = f32x4{0.f,0.f,0.f,0.f};

    for (int h = 0; h < H_; ++h) {
        const bf16* qrow = Q + ((size_t)(b * H_ + h) * S_ + q0 + l16) * DK_;
        bf16x8 qf0 = ld8(qrow + quad*8), qf1 = ld8(qrow + 32 + quad*8);
        const bf16* Kb = K + (size_t)(b * H_ + h) * S_ * DK_;
        float li[4];
#pragma unroll
        for (int r = 0; r < 4; ++r) li[r] = linv[h][quad*4 + r];

#pragma unroll
        for (int t = 0; t < 4; ++t) {
            const int jl = wv*64 + t*16;
            const bf16* krow = Kb + (size_t)(j0 + jl + l16) * DK_;
            bf16x8 kf0 = ld8(krow + quad*8), kf1 = ld8(krow + 32 + quad*8);
            f32x4 s = {0.f,0.f,0.f,0.f};
            s = __builtin_amdgcn_mfma_f32_16x16x32_bf16(qf0, kf0, s, 0, 0, 0);
            s = __builtin_amdgcn_mfma_f32_16x16x32_bf16(qf1, kf1, s, 0, 0, 0);
#pragma unroll
            for (int r = 0; r < 4; ++r)
                asum[t][r] += __expf(fminf(s[r] * 0.125f, 60.f)) * li[r];
        }
    }
#pragma unroll
    for (int t = 0; t < 4; ++t)
#pragma unroll
        for (int r = 0; r < 4; ++r)
            attnOut[((size_t)b * S_ + q0 + quad*4 + r) * S_ + j0 + wv*64 + t*16 + l16]
                = asum[t][r] * (1.0f / H_);
}

// ---------------------------------------------------------------------------
// Context: one block per (q-tile16, head, b). Wave w owns j in [512w,512w+512).
// P transposed through wave-private LDS (no barrier). PV via swapped operands:
// C[d][q] += V^T(16d x 32j) . P^T(32j x 16q). One barrier for cross-wave reduce.
// Writes ctx (bf16) over the block's own Q rows.
// ---------------------------------------------------------------------------
__global__ __launch_bounds__(256)
void attn_ctx(const bf16* __restrict__ Q, const bf16* __restrict__ K,
              const bf16* __restrict__ V, const float* __restrict__ Li,
              bf16* __restrict__ ctxOutQ)
{
    const int q0 = blockIdx.x * 16, h = blockIdx.y, b = blockIdx.z;
    const int tid = threadIdx.x;
    const int wv = tid >> 6, lane = tid & 63, quad = lane >> 4, l16 = lane & 15;

    __shared__ __align__(16) bf16 Pw[4][16][40];   // row stride 80B (16B-aligned)
    __shared__ float ctxp[4][1024];                // 16 KB

    const size_t hb = (size_t)(b * H_ + h) * S_;
    const bf16* qrow = Q + (hb + q0 + l16) * DK_;
    bf16x8 qf0 = ld8(qrow + quad*8), qf1 = ld8(qrow + 32 + quad*8);
    const bf16* Kb = K + hb * DK_;
    const bf16* Vb = V + hb * DK_;

    float li[4];
#pragma unroll
    for (int r = 0; r < 4; ++r)
        li[r] = 1.0f / fmaxf(Li[hb + q0 + quad*4 + r], 1e-30f);

    f32x4 cacc[4];
#pragma unroll
    for (int d = 0; d < 4; ++d) cacc[d] = f32x4{0.f,0.f,0.f,0.f};

    for (int jc = 0; jc < 16; ++jc) {
        const int j0 = wv * 512 + jc * 32;
        f32x4 s[2];
#pragma unroll
        for (int jt = 0; jt < 2; ++jt) {
            const bf16* krow = Kb + (size_t)(j0 + jt*16 + l16) * DK_;
            bf16x8 kf0 = ld8(krow + quad*8), kf1 = ld8(krow + 32 + quad*8);
            f32x4 z = {0.f,0.f,0.f,0.f};
            z = __builtin_amdgcn_mfma_f32_16x16x32_bf16(qf0, kf0, z, 0, 0, 0);
            s[jt] = __builtin_amdgcn_mfma_f32_16x16x32_bf16(qf1, kf1, z, 0, 0, 0);
        }
#pragma unroll
        for (int jt = 0; jt < 2; ++jt)
#pragma unroll
            for (int r = 0; r < 4; ++r)
                Pw[wv][quad*4 + r][jt*16 + l16] =
                    (bf16)(__expf(fminf(s[jt][r] * 0.125f, 60.f)) * li[r]);

        // wave-internal transpose read (same-wave LDS ordering; no barrier)
        bf16x8 pa = *(const bf16x8*)&Pw[wv][l16][quad*8];
#pragma unroll
        for (int db = 0; db < 4; ++db) {
            bf16x8 va;
#pragma unroll
            for (int jj = 0; jj < 8; ++jj)
                va[jj] = Vb[(size_t)(j0 + quad*8 + jj) * DK_ + db*16 + l16];
            cacc[db] = __builtin_amdgcn_mfma_f32_16x16x32_bf16(va, pa, cacc[db], 0, 0, 0);
        }
    }

#pragma unroll
    for (int db = 0; db < 4; ++db)
#pragma unroll
        for (int r = 0; r < 4; ++r)
            ctxp[wv][(db*16 + quad*4 + r) * 16 + l16] = cacc[db][r];
    __syncthreads();
#pragma unroll
    for (int i = 0; i < 4; ++i) {
        const int e = tid * 4 + i;
        float v = ctxp[0][e] + ctxp[1][e] + ctxp[2][e] + ctxp[3][e];
        const int d = e >> 4, q = e & 15;
        ctxOutQ[(hb + q0 + q) * DK_ + d] = (bf16)v;
    }
}

// ---------------------------------------------------------------------------
extern "C" void kernel_launch(void* const* d_in, const int* in_sizes, int n_in,
                              void* d_out, int out_size, void* d_ws, size_t ws_size,
                              hipStream_t stream)
{
    (void)in_sizes; (void)n_in; (void)out_size; (void)ws_size;

    const float* query = (const float*)d_in[0];
    const float* key_t = (const float*)d_in[1];
    const float* value = (const float*)d_in[2];
    const float* Wq = (const float*)d_in[3];
    const float* bq = (const float*)d_in[4];
    const float* Wk = (const float*)d_in[5];
    const float* bk = (const float*)d_in[6];
    const float* Wv = (const float*)d_in[7];
    const float* bv = (const float*)d_in[8];
    const float* Wo = (const float*)d_in[9];
    const float* bo = (const float*)d_in[10];

    float* out     = (float*)d_out;                  // (B,S,D) fp32, bytes 0..16.8MB
    float* attnOut = out + (size_t)B_ * S_ * D_;     // (B,S,S) fp32, bytes 16.8..50.3MB

    const size_t nX = (size_t)B_ * S_ * D_;          // 4.19M
    const size_t nW = (size_t)D_ * D_;               // 1.05M

    // d_out doubles as scratch for bf16 X-converts until attn_weights/gemm_out
    // overwrite it (stream-ordered; Xv tail overlaps attnOut start but is dead
    // by then).
    bf16* Xqb = (bf16*)d_out;
    bf16* Xkb = Xqb + nX;
    bf16* Xvb = Xkb + nX;

    // ws: Q,K,V (25.2MB) + W converts (8MB) + Li (0.25MB) = 33.8MB
    bf16* Qh  = (bf16*)d_ws;
    bf16* Kh  = Qh + nX;
    bf16* Vh  = Kh + nX;
    bf16* Wqb = Vh + nX;
    bf16* Wkb = Wqb + nW;
    bf16* Wvb = Wkb + nW;
    bf16* Wob = Wvb + nW;
    float* Li = (float*)(Wob + nW);                  // B*H*S fp32

    cvt_all<<<8192, 256, 0, stream>>>(query, key_t, value, Wq, Wk, Wv, Wo,
                                      Xqb, Xkb, Xvb, Wqb, Wkb, Wvb, Wob);
    dim3 gg(M_/128, D_/128);
    gemm128<<<gg, 256, 0, stream>>>(Xqb, Wqb, bq, Qh, 0, 0);
    gemm128<<<gg, 256, 0, stream>>>(Xkb, Wkb, bk, Kh, 0, 0);
    gemm128<<<gg, 256, 0, stream>>>(Xvb, Wvb, bv, Vh, 0, 0);
    attn_sum    <<<dim3(S_/16, H_, B_), 256, 0, stream>>>(Qh, Kh, Li);
    attn_weights<<<dim3(S_/16, S_/256, B_), 256, 0, stream>>>(Qh, Kh, Li, attnOut);
    attn_ctx    <<<dim3(S_/16, H_, B_), 256, 0, stream>>>(Qh, Kh, Vh, Li, Qh);
    gemm128<<<gg, 256, 0, stream>>>(Qh, Wob, bo, out, 1, 1);
}

// Round 6
// 397.943 us; speedup vs baseline: 3.3374x; 1.6777x over previous
//
#include <hip/hip_runtime.h>

// Problem constants (B,S,D,H from reference)
#define B_ 2
#define S_ 2048
#define D_ 1024
#define H_ 16
#define DK_ 64
#define M_ (B_ * S_)      // 4096 rows in the projection GEMMs

typedef __bf16 bf16;
typedef __attribute__((ext_vector_type(8))) __bf16 bf16x8;
typedef __attribute__((ext_vector_type(4))) __bf16 bf16x4;
typedef __attribute__((ext_vector_type(4))) float f32x4;

static __device__ __forceinline__ bf16x8 ld8(const bf16* p) {
    return *(const bf16x8*)p;   // 16B aligned by construction
}

// ---------------------------------------------------------------------------
// Elementwise fp32 -> bf16 for the 3 X inputs (into d_out scratch) and the
// 4 weight matrices (into ws). Block mapping: 3*2048 X-blocks + 4*512 W-blocks.
// ---------------------------------------------------------------------------
__global__ __launch_bounds__(256)
void cvt_all(const float* __restrict__ xq, const float* __restrict__ xk,
             const float* __restrict__ xv, const float* __restrict__ wq,
             const float* __restrict__ wk, const float* __restrict__ wv,
             const float* __restrict__ wo, bf16* __restrict__ xqo,
             bf16* __restrict__ xko, bf16* __restrict__ xvo,
             bf16* __restrict__ wqo, bf16* __restrict__ wko,
             bf16* __restrict__ wvo, bf16* __restrict__ woo)
{
    const int bx = blockIdx.x;
    const float* s; bf16* d; size_t base;
    if (bx < 6144) {
        int a = bx >> 11;
        s = (a == 0) ? xq : (a == 1) ? xk : xv;
        d = (a == 0) ? xqo : (a == 1) ? xko : xvo;
        base = (size_t)(bx & 2047) * 2048;
    } else {
        int a = (bx - 6144) >> 9;
        s = (a == 0) ? wq : (a == 1) ? wk : (a == 2) ? wv : wo;
        d = (a == 0) ? wqo : (a == 1) ? wko : (a == 2) ? wvo : woo;
        base = (size_t)((bx - 6144) & 511) * 2048;
    }
    size_t i = base + (size_t)threadIdx.x * 8;
    f32x4 a4 = *(const f32x4*)(s + i);
    f32x4 b4 = *(const f32x4*)(s + i + 4);
    bf16x8 r;
    r[0]=(bf16)a4[0]; r[1]=(bf16)a4[1]; r[2]=(bf16)a4[2]; r[3]=(bf16)a4[3];
    r[4]=(bf16)b4[0]; r[5]=(bf16)b4[1]; r[6]=(bf16)b4[2]; r[7]=(bf16)b4[3];
    *(bf16x8*)(d + i) = r;
}

// ---------------------------------------------------------------------------
// 128x128-tile bf16 GEMM, LDS-staged, 2-barrier K-loop.
// out_mode: 0 = bf16 head-split (B,H,S,DK);  1 = fp32 flat (M,N);
//           2 = bf16 TRANSPOSED head-split (B,H,DK,S)  [for V^T]
// a_headsplit: A element (m,k) at ((b*H+h)*S+s)*DK+dk (ctx layout).
// ---------------------------------------------------------------------------
__global__ __launch_bounds__(256)
void gemm128(const bf16* __restrict__ A, const bf16* __restrict__ W,
             const float* __restrict__ bias, void* __restrict__ out,
             int a_headsplit, int out_mode)
{
    const int m0 = blockIdx.x * 128, n0 = blockIdx.y * 128;
    const int tid = threadIdx.x;
    const int wv = tid >> 6, lane = tid & 63, quad = lane >> 4, l16 = lane & 15;
    const int wr = (wv >> 1) * 64, wc = (wv & 1) * 64;

    __shared__ bf16 As[128 * 32];
    __shared__ bf16 Bs[128 * 32];

    f32x4 acc[4][4];
#pragma unroll
    for (int i = 0; i < 4; ++i)
#pragma unroll
        for (int j = 0; j < 4; ++j) acc[i][j] = f32x4{0.f, 0.f, 0.f, 0.f};

    const int srow = tid >> 2;
    const int scol = (tid & 3) * 8;

    for (int k0 = 0; k0 < D_; k0 += 32) {
        bf16x8 av[2], bw[2];
#pragma unroll
        for (int c = 0; c < 2; ++c) {
            const int row = c * 64 + srow;
            const int k   = k0 + scol;
            const bf16* ap;
            if (a_headsplit) {
                int m = m0 + row, bb = m >> 11, ss = m & (S_ - 1);
                int hh = k >> 6, dd = k & (DK_ - 1);
                ap = A + (((size_t)(bb * H_ + hh) * S_ + ss) * DK_ + dd);
            } else {
                ap = A + (size_t)(m0 + row) * D_ + k;
            }
            av[c] = ld8(ap);
            bw[c] = ld8(W + (size_t)(n0 + row) * D_ + k);
        }
        __syncthreads();
#pragma unroll
        for (int c = 0; c < 2; ++c) {
            const int e = c * 2048 + tid * 8;
            *(bf16x8*)(As + e) = av[c];
            *(bf16x8*)(Bs + e) = bw[c];
        }
        __syncthreads();

        bf16x8 af[4], bfr[4];
#pragma unroll
        for (int i = 0; i < 4; ++i)
            af[i] = *(const bf16x8*)(As + (wr + i*16 + l16) * 32 + quad * 8);
#pragma unroll
        for (int j = 0; j < 4; ++j)
            bfr[j] = *(const bf16x8*)(Bs + (wc + j*16 + l16) * 32 + quad * 8);
#pragma unroll
        for (int i = 0; i < 4; ++i)
#pragma unroll
            for (int j = 0; j < 4; ++j)
                acc[i][j] = __builtin_amdgcn_mfma_f32_16x16x32_bf16(
                    af[i], bfr[j], acc[i][j], 0, 0, 0);
    }

#pragma unroll
    for (int i = 0; i < 4; ++i)
#pragma unroll
        for (int j = 0; j < 4; ++j) {
            const int nn = n0 + wc + j*16 + l16;
            const float bvv = bias[nn];
            const int mm0 = m0 + wr + i*16 + quad*4;   // 4-aligned, same b
            if (out_mode == 2) {
                // V^T: (B,H,DK,S); 4 consecutive tokens -> one 8B store
                bf16x4 pk;
#pragma unroll
                for (int r = 0; r < 4; ++r) pk[r] = (bf16)(acc[i][j][r] + bvv);
                int bb = mm0 >> 11, ss = mm0 & (S_ - 1);
                int hh = nn >> 6,  dd = nn & (DK_ - 1);
                *(bf16x4*)((bf16*)out +
                    ((size_t)(bb * H_ + hh) * DK_ + dd) * S_ + ss) = pk;
            } else {
#pragma unroll
                for (int r = 0; r < 4; ++r) {
                    const int mm = mm0 + r;
                    float v = acc[i][j][r] + bvv;
                    if (out_mode == 1) {
                        ((float*)out)[(size_t)mm * D_ + nn] = v;
                    } else {
                        int bb = mm >> 11, ss = mm & (S_ - 1);
                        int hh = nn >> 6, dd = nn & (DK_ - 1);
                        ((bf16*)out)[((size_t)(bb * H_ + hh) * S_ + ss) * DK_ + dd] = (bf16)v;
                    }
                }
            }
        }
}

// ---------------------------------------------------------------------------
// Softmax denominators: block = (q-tile64, head, b); waves stride over j.
// Each K fragment feeds 4 q-tiles.
// ---------------------------------------------------------------------------
__global__ __launch_bounds__(256)
void attn_sum(const bf16* __restrict__ Q, const bf16* __restrict__ K,
              float* __restrict__ Lo)
{
    const int q0 = blockIdx.x * 64, h = blockIdx.y, b = blockIdx.z;
    const int tid = threadIdx.x;
    const int wv = tid >> 6, lane = tid & 63, quad = lane >> 4, l16 = lane & 15;
    const size_t hb = (size_t)(b * H_ + h) * S_;

    bf16x8 qf[4][2];
#pragma unroll
    for (int qt = 0; qt < 4; ++qt) {
        const bf16* qrow = Q + (hb + q0 + qt*16 + l16) * DK_;
        qf[qt][0] = ld8(qrow + quad*8);
        qf[qt][1] = ld8(qrow + 32 + quad*8);
    }
    const bf16* Kb = K + hb * DK_;

    float lsum[4][4];
#pragma unroll
    for (int qt = 0; qt < 4; ++qt)
#pragma unroll
        for (int r = 0; r < 4; ++r) lsum[qt][r] = 0.f;

    for (int jt = wv; jt < S_/16; jt += 4) {
        const bf16* krow = Kb + (size_t)(jt*16 + l16) * DK_;
        bf16x8 kf0 = ld8(krow + quad*8), kf1 = ld8(krow + 32 + quad*8);
#pragma unroll
        for (int qt = 0; qt < 4; ++qt) {
            f32x4 z = {0.f,0.f,0.f,0.f};
            z = __builtin_amdgcn_mfma_f32_16x16x32_bf16(qf[qt][0], kf0, z, 0, 0, 0);
            f32x4 s = __builtin_amdgcn_mfma_f32_16x16x32_bf16(qf[qt][1], kf1, z, 0, 0, 0);
#pragma unroll
            for (int r = 0; r < 4; ++r)
                lsum[qt][r] += __expf(fminf(s[r] * 0.125f, 60.f));
        }
    }
#pragma unroll
    for (int d = 1; d < 16; d <<= 1)
#pragma unroll
        for (int qt = 0; qt < 4; ++qt)
#pragma unroll
            for (int r = 0; r < 4; ++r)
                lsum[qt][r] += __shfl_xor(lsum[qt][r], d);

    __shared__ float wp[4][4][16];
    if (l16 == 0)
#pragma unroll
        for (int qt = 0; qt < 4; ++qt)
#pragma unroll
            for (int r = 0; r < 4; ++r) wp[wv][qt][quad*4 + r] = lsum[qt][r];
    __syncthreads();
    if (tid < 64) {
        int qt = tid >> 4, row = tid & 15;
        Lo[hb + q0 + qt*16 + row] =
            wp[0][qt][row] + wp[1][qt][row] + wp[2][qt][row] + wp[3][qt][row];
    }
}

// ---------------------------------------------------------------------------
// Head-mean attention weights: block = (q-tile64, j-chunk256, b).
// Wave w owns j sub-range [64w,64w+64) of the chunk; K frags feed 4 q-tiles;
// accumulates over all 16 heads in registers; no inner barriers.
// ---------------------------------------------------------------------------
__global__ __launch_bounds__(256)
void attn_weights(const bf16* __restrict__ Q, const bf16* __restrict__ K,
                  const float* __restrict__ Li, float* __restrict__ attnOut)
{
    const int q0 = blockIdx.x * 64, j0 = blockIdx.y * 256, b = blockIdx.z;
    const int tid = threadIdx.x;
    const int wv = tid >> 6, lane = tid & 63, quad = lane >> 4, l16 = lane & 15;

    __shared__ float linv[H_][64];
#pragma unroll
    for (int i = 0; i < 4; ++i) {
        int idx = tid * 4 + i;
        int hh = idx >> 6, row = idx & 63;
        linv[hh][row] =
            1.0f / fmaxf(Li[(size_t)(b * H_ + hh) * S_ + q0 + row], 1e-30f);
    }
    __syncthreads();

    f32x4 asum[4][4];
#pragma unroll
    for (int qt = 0; qt < 4; ++qt)
#pragma unroll
        for (int t = 0; t < 4; ++t) asum[qt][t] = f32x4{0.f,0.f,0.f,0.f};

    for (int h = 0; h < H_; ++h) {
        const size_t hb = (size_t)(b * H_ + h) * S_;
        bf16x8 qf[4][2];
#pragma unroll
        for (int qt = 0; qt < 4; ++qt) {
            const bf16* qrow = Q + (hb + q0 + qt*16 + l16) * DK_;
            qf[qt][0] = ld8(qrow + quad*8);
            qf[qt][1] = ld8(qrow + 32 + quad*8);
        }
        const bf16* Kb = K + hb * DK_;
#pragma unroll
        for (int t = 0; t < 4; ++t) {
            const int jl = j0 + wv*64 + t*16;
            const bf16* krow = Kb + (size_t)(jl + l16) * DK_;
            bf16x8 kf0 = ld8(krow + quad*8), kf1 = ld8(krow + 32 + quad*8);
#pragma unroll
            for (int qt = 0; qt < 4; ++qt) {
                f32x4 z = {0.f,0.f,0.f,0.f};
                z = __builtin_amdgcn_mfma_f32_16x16x32_bf16(qf[qt][0], kf0, z, 0, 0, 0);
                f32x4 s = __builtin_amdgcn_mfma_f32_16x16x32_bf16(qf[qt][1], kf1, z, 0, 0, 0);
#pragma unroll
                for (int r = 0; r < 4; ++r)
                    asum[qt][t][r] += __expf(fminf(s[r] * 0.125f, 60.f))
                                      * linv[h][qt*16 + quad*4 + r];
            }
        }
    }
#pragma unroll
    for (int qt = 0; qt < 4; ++qt)
#pragma unroll
        for (int t = 0; t < 4; ++t)
#pragma unroll
            for (int r = 0; r < 4; ++r)
                attnOut[((size_t)b * S_ + q0 + qt*16 + quad*4 + r) * S_
                        + j0 + wv*64 + t*16 + l16] = asum[qt][t][r] * (1.0f / H_);
}

// ---------------------------------------------------------------------------
// Context: block = (q-tile64, head, b). Wave w owns j in [512w, 512w+512).
// V^T (B,H,DK,S) gives contiguous ld8 V fragments; K and V^T frags feed 4
// q-tiles. P transposed via wave-private LDS (no barrier). Cross-wave ctx
// reduce per q-tile through padded LDS. ctx overwrites the block's own Q rows.
// ---------------------------------------------------------------------------
__global__ __launch_bounds__(256)
void attn_ctx(const bf16* __restrict__ Q, const bf16* __restrict__ K,
              const bf16* __restrict__ Vt, const float* __restrict__ Li,
              bf16* __restrict__ ctxOutQ)
{
    const int q0 = blockIdx.x * 64, h = blockIdx.y, b = blockIdx.z;
    const int tid = threadIdx.x;
    const int wv = tid >> 6, lane = tid & 63, quad = lane >> 4, l16 = lane & 15;

    __shared__ __align__(16) bf16 Pw[4][4][16][40];  // [wv][qt][q16][j32+pad] 20.5 KB
    __shared__ float ctxp[4][64*17 + 16];            // [wv][dk*17+q]          17.5 KB

    const size_t hb = (size_t)(b * H_ + h) * S_;
    bf16x8 qf[4][2];
#pragma unroll
    for (int qt = 0; qt < 4; ++qt) {
        const bf16* qrow = Q + (hb + q0 + qt*16 + l16) * DK_;
        qf[qt][0] = ld8(qrow + quad*8);
        qf[qt][1] = ld8(qrow + 32 + quad*8);
    }
    const bf16* Kb  = K  + hb * DK_;
    const bf16* Vtb = Vt + hb * DK_;   // (B,H,DK,S): row d at Vtb + d*S

    float li[4][4];
#pragma unroll
    for (int qt = 0; qt < 4; ++qt)
#pragma unroll
        for (int r = 0; r < 4; ++r)
            li[qt][r] = 1.0f / fmaxf(Li[hb + q0 + qt*16 + quad*4 + r], 1e-30f);

    f32x4 cacc[4][4];   // [db][qt]
#pragma unroll
    for (int db = 0; db < 4; ++db)
#pragma unroll
        for (int qt = 0; qt < 4; ++qt) cacc[db][qt] = f32x4{0.f,0.f,0.f,0.f};

    for (int jc = 0; jc < 16; ++jc) {
        const int j0 = wv * 512 + jc * 32;
        // K fragments for the two 16-j tiles (reused by 4 q-tiles)
        const bf16* kr0 = Kb + (size_t)(j0 + l16) * DK_;
        const bf16* kr1 = Kb + (size_t)(j0 + 16 + l16) * DK_;
        bf16x8 kf0a = ld8(kr0 + quad*8), kf0b = ld8(kr0 + 32 + quad*8);
        bf16x8 kf1a = ld8(kr1 + quad*8), kf1b = ld8(kr1 + 32 + quad*8);

#pragma unroll
        for (int qt = 0; qt < 4; ++qt) {
            f32x4 z0 = {0.f,0.f,0.f,0.f}, z1 = {0.f,0.f,0.f,0.f};
            z0 = __builtin_amdgcn_mfma_f32_16x16x32_bf16(qf[qt][0], kf0a, z0, 0, 0, 0);
            f32x4 s0 = __builtin_amdgcn_mfma_f32_16x16x32_bf16(qf[qt][1], kf0b, z0, 0, 0, 0);
            z1 = __builtin_amdgcn_mfma_f32_16x16x32_bf16(qf[qt][0], kf1a, z1, 0, 0, 0);
            f32x4 s1 = __builtin_amdgcn_mfma_f32_16x16x32_bf16(qf[qt][1], kf1b, z1, 0, 0, 0);
#pragma unroll
            for (int r = 0; r < 4; ++r) {
                Pw[wv][qt][quad*4 + r][l16] =
                    (bf16)(__expf(fminf(s0[r] * 0.125f, 60.f)) * li[qt][r]);
                Pw[wv][qt][quad*4 + r][16 + l16] =
                    (bf16)(__expf(fminf(s1[r] * 0.125f, 60.f)) * li[qt][r]);
            }
        }
        // V^T fragments: contiguous in j (reused by 4 q-tiles)
#pragma unroll
        for (int db = 0; db < 4; ++db) {
            bf16x8 va = ld8(Vtb + (size_t)(db*16 + l16) * S_ + j0 + quad*8);
#pragma unroll
            for (int qt = 0; qt < 4; ++qt) {
                bf16x8 pa = *(const bf16x8*)&Pw[wv][qt][l16][quad*8];
                cacc[db][qt] = __builtin_amdgcn_mfma_f32_16x16x32_bf16(
                    va, pa, cacc[db][qt], 0, 0, 0);
            }
        }
    }

    // cross-wave reduce + write, one q-tile at a time
#pragma unroll
    for (int qt = 0; qt < 4; ++qt) {
        __syncthreads();   // previous round's reads complete
#pragma unroll
        for (int db = 0; db < 4; ++db)
#pragma unroll
            for (int r = 0; r < 4; ++r)
                ctxp[wv][(db*16 + quad*4 + r) * 17 + l16] = cacc[db][qt][r];
        __syncthreads();
        {
            const int q  = tid >> 4;          // 0..15
            const int d0 = (tid & 15) * 4;    // 0,4,..,60
            bf16x4 pk;
#pragma unroll
            for (int i = 0; i < 4; ++i) {
                const int e = (d0 + i) * 17 + q;
                pk[i] = (bf16)(ctxp[0][e] + ctxp[1][e] + ctxp[2][e] + ctxp[3][e]);
            }
            *(bf16x4*)(ctxOutQ + (hb + q0 + qt*16 + q) * DK_ + d0) = pk;
        }
    }
}

// ---------------------------------------------------------------------------
extern "C" void kernel_launch(void* const* d_in, const int* in_sizes, int n_in,
                              void* d_out, int out_size, void* d_ws, size_t ws_size,
                              hipStream_t stream)
{
    (void)in_sizes; (void)n_in; (void)out_size; (void)ws_size;

    const float* query = (const float*)d_in[0];
    const float* key_t = (const float*)d_in[1];
    const float* value = (const float*)d_in[2];
    const float* Wq = (const float*)d_in[3];
    const float* bq = (const float*)d_in[4];
    const float* Wk = (const float*)d_in[5];
    const float* bk = (const float*)d_in[6];
    const float* Wv = (const float*)d_in[7];
    const float* bv = (const float*)d_in[8];
    const float* Wo = (const float*)d_in[9];
    const float* bo = (const float*)d_in[10];

    float* out     = (float*)d_out;                  // (B,S,D) fp32
    float* attnOut = out + (size_t)B_ * S_ * D_;     // (B,S,S) fp32

    const size_t nX = (size_t)B_ * S_ * D_;
    const size_t nW = (size_t)D_ * D_;

    // d_out doubles as scratch for bf16 X-converts (dead before overwrites)
    bf16* Xqb = (bf16*)d_out;
    bf16* Xkb = Xqb + nX;
    bf16* Xvb = Xkb + nX;

    // ws: Q,K,V^T (25.2MB) + W converts (8.4MB) + Li (0.26MB) = 33.8MB
    bf16* Qh  = (bf16*)d_ws;
    bf16* Kh  = Qh + nX;
    bf16* VtH = Kh + nX;                             // V^T (B,H,DK,S)
    bf16* Wqb = VtH + nX;
    bf16* Wkb = Wqb + nW;
    bf16* Wvb = Wkb + nW;
    bf16* Wob = Wvb + nW;
    float* Li = (float*)(Wob + nW);

    cvt_all<<<8192, 256, 0, stream>>>(query, key_t, value, Wq, Wk, Wv, Wo,
                                      Xqb, Xkb, Xvb, Wqb, Wkb, Wvb, Wob);
    dim3 gg(M_/128, D_/128);
    gemm128<<<gg, 256, 0, stream>>>(Xqb, Wqb, bq, Qh, 0, 0);
    gemm128<<<gg, 256, 0, stream>>>(Xkb, Wkb, bk, Kh, 0, 0);
    gemm128<<<gg, 256, 0, stream>>>(Xvb, Wvb, bv, VtH, 0, 2);   // V^T layout
    attn_sum    <<<dim3(S_/64, H_, B_), 256, 0, stream>>>(Qh, Kh, Li);
    attn_weights<<<dim3(S_/64, S_/256, B_), 256, 0, stream>>>(Qh, Kh, Li, attnOut);
    attn_ctx    <<<dim3(S_/64, H_, B_), 256, 0, stream>>>(Qh, Kh, VtH, Li, Qh);
    gemm128<<<gg, 256, 0, stream>>>(Qh, Wob, bo, out, 1, 1);
}